// Round 1
// baseline (216.243 us; speedup 1.0000x reference)
//
#include <hip/hip_runtime.h>

#define WIRES 14
#define NSTATE (1 << WIRES)   // 16384
#define NTH 1024
#define NQUADS (NSTATE / 4)   // 4096
#define NVB 13                // variational blocks

// ---- LDS bank swizzle on float2 index: spread forced-zero pair bits ----
__device__ __forceinline__ int phys(int i) { return i ^ (((i >> 4) & 3) << 2); }

__device__ __forceinline__ float2 cmul(float2 a, float2 b) {
    return make_float2(a.x * b.x - a.y * b.y, a.x * b.y + a.y * b.x);
}

// ============ kernel 1: fuse each 10-gate variational block into one 4x4 ============
__global__ void gate_prep(const float* __restrict__ params, float2* __restrict__ G) {
    int k = threadIdx.x;
    if (k >= NVB) return;
    const float* p = params + k * 10;

    float2 U1[4], U2[4], U3[4], U4[4];
    auto rzrx = [](float trx, float trz, float2* U) {
        float cx, sx, cz, sz;
        sincosf(trx * 0.5f, &sx, &cx);
        sincosf(trz * 0.5f, &sz, &cz);
        float2 e0 = make_float2(cz, -sz);   // e^{-i h}
        float2 e1 = make_float2(cz,  sz);   // e^{+i h}
        // U = Rz * Rx ; Rx = [[c, -i s],[-i s, c]]
        U[0] = cmul(e0, make_float2(cx, 0.f));
        U[1] = cmul(e0, make_float2(0.f, -sx));
        U[2] = cmul(e1, make_float2(0.f, -sx));
        U[3] = cmul(e1, make_float2(cx, 0.f));
    };
    rzrx(p[0], p[1], U1);   // q1, first
    rzrx(p[2], p[3], U2);   // q2, first
    rzrx(p[5], p[6], U3);   // q1, second
    rzrx(p[7], p[8], U4);   // q2, second

    float2 K12[16], K34[16];
    for (int r1 = 0; r1 < 2; ++r1)
        for (int r2 = 0; r2 < 2; ++r2)
            for (int c1 = 0; c1 < 2; ++c1)
                for (int c2 = 0; c2 < 2; ++c2) {
                    int idx = (r1 * 2 + r2) * 4 + (c1 * 2 + c2);
                    K12[idx] = cmul(U1[r1 * 2 + c1], U2[r2 * 2 + c2]);
                    K34[idx] = cmul(U3[r1 * 2 + c1], U4[r2 * 2 + c2]);
                }

    float2 C1[16], C2[16];
    for (int i = 0; i < 16; ++i) { C1[i] = make_float2(0.f, 0.f); C2[i] = make_float2(0.f, 0.f); }
    {
        float c, s;
        sincosf(p[4] * 0.5f, &s, &c);        // CRY ctrl=q1(high local bit), tgt=q2
        C1[0]  = make_float2(1.f, 0.f); C1[5]  = make_float2(1.f, 0.f);
        C1[10] = make_float2(c, 0.f);   C1[11] = make_float2(-s, 0.f);
        C1[14] = make_float2(s, 0.f);   C1[15] = make_float2(c, 0.f);
        sincosf(p[9] * 0.5f, &s, &c);        // CRY ctrl=q2(low local bit), tgt=q1
        C2[0]  = make_float2(1.f, 0.f); C2[10] = make_float2(1.f, 0.f);
        C2[5]  = make_float2(c, 0.f);   C2[7]  = make_float2(-s, 0.f);
        C2[13] = make_float2(s, 0.f);   C2[15] = make_float2(c, 0.f);
    }

    float2 T1[16], T2[16], Gk[16];
    for (int r = 0; r < 4; ++r)
        for (int c = 0; c < 4; ++c) {
            float2 a = make_float2(0.f, 0.f);
            for (int j = 0; j < 4; ++j) { float2 m = cmul(C1[r*4+j], K12[j*4+c]); a.x += m.x; a.y += m.y; }
            T1[r*4+c] = a;
        }
    for (int r = 0; r < 4; ++r)
        for (int c = 0; c < 4; ++c) {
            float2 a = make_float2(0.f, 0.f);
            for (int j = 0; j < 4; ++j) { float2 m = cmul(K34[r*4+j], T1[j*4+c]); a.x += m.x; a.y += m.y; }
            T2[r*4+c] = a;
        }
    for (int r = 0; r < 4; ++r)
        for (int c = 0; c < 4; ++c) {
            float2 a = make_float2(0.f, 0.f);
            for (int j = 0; j < 4; ++j) { float2 m = cmul(C2[r*4+j], T2[j*4+c]); a.x += m.x; a.y += m.y; }
            Gk[r*4+c] = a;
        }
    for (int i = 0; i < 16; ++i) G[k * 16 + i] = Gk[i];
}

// ============ sweeps: one 4x4 gate on adjacent bit pair (BB+1, BB) ============
template <int BB>
__device__ __forceinline__ void sweepR(float2* st, const float* g, int tid) {
    constexpr int M = (1 << BB) - 1;
    #pragma unroll
    for (int it = 0; it < NQUADS / NTH; ++it) {
        int p = tid + it * NTH;
        int i0 = ((p & ~M) << 2) | (p & M);
        int j0 = phys(i0);
        int j1 = phys(i0 + (1 << BB));
        int j2 = phys(i0 + (2 << BB));
        int j3 = phys(i0 + (3 << BB));
        float2 v0 = st[j0], v1 = st[j1], v2 = st[j2], v3 = st[j3];
        float2 w0, w1, w2, w3;
        w0.x = g[0]*v0.x + g[1]*v1.x + g[2]*v2.x + g[3]*v3.x;
        w0.y = g[0]*v0.y + g[1]*v1.y + g[2]*v2.y + g[3]*v3.y;
        w1.x = g[4]*v0.x + g[5]*v1.x + g[6]*v2.x + g[7]*v3.x;
        w1.y = g[4]*v0.y + g[5]*v1.y + g[6]*v2.y + g[7]*v3.y;
        w2.x = g[8]*v0.x + g[9]*v1.x + g[10]*v2.x + g[11]*v3.x;
        w2.y = g[8]*v0.y + g[9]*v1.y + g[10]*v2.y + g[11]*v3.y;
        w3.x = g[12]*v0.x + g[13]*v1.x + g[14]*v2.x + g[15]*v3.x;
        w3.y = g[12]*v0.y + g[13]*v1.y + g[14]*v2.y + g[15]*v3.y;
        st[j0] = w0; st[j1] = w1; st[j2] = w2; st[j3] = w3;
    }
}

template <int BB>
__device__ __forceinline__ void sweepC(float2* st, const float2* G, int tid) {
    constexpr int M = (1 << BB) - 1;
    #pragma unroll
    for (int it = 0; it < NQUADS / NTH; ++it) {
        int p = tid + it * NTH;
        int i0 = ((p & ~M) << 2) | (p & M);
        int j0 = phys(i0);
        int j1 = phys(i0 + (1 << BB));
        int j2 = phys(i0 + (2 << BB));
        int j3 = phys(i0 + (3 << BB));
        float2 v0 = st[j0], v1 = st[j1], v2 = st[j2], v3 = st[j3];
        float2 w0, w1, w2, w3;
#define CROW(R, W)                                                                     \
        W.x = G[4*R+0].x*v0.x - G[4*R+0].y*v0.y + G[4*R+1].x*v1.x - G[4*R+1].y*v1.y    \
            + G[4*R+2].x*v2.x - G[4*R+2].y*v2.y + G[4*R+3].x*v3.x - G[4*R+3].y*v3.y;   \
        W.y = G[4*R+0].x*v0.y + G[4*R+0].y*v0.x + G[4*R+1].x*v1.y + G[4*R+1].y*v1.x    \
            + G[4*R+2].x*v2.y + G[4*R+2].y*v2.x + G[4*R+3].x*v3.y + G[4*R+3].y*v3.x;
        CROW(0, w0) CROW(1, w1) CROW(2, w2) CROW(3, w3)
#undef CROW
        st[j0] = w0; st[j1] = w1; st[j2] = w2; st[j3] = w3;
    }
}

// ============ kernel 2: full per-sample simulation in LDS ============
__global__ __launch_bounds__(NTH) void sim(const float* __restrict__ inputs,
                                           const float2* __restrict__ gates,
                                           float* __restrict__ out) {
    __shared__ float2 st[NSTATE];   // 128 KiB
    const int b = blockIdx.x;
    const int tid = threadIdx.x;

    for (int i = tid; i < NSTATE; i += NTH)
        st[phys(i)] = make_float2(i == 0 ? 1.f : 0.f, 0.f);
    __syncthreads();

    const float* inp = inputs + b * WIRES;

    // ---- RY encoding, fused in adjacent pairs (real 4x4 kron) ----
    float g[16];
#define ENC(J, BBv) {                                                   \
        float c1, s1, c2, s2;                                           \
        sincosf(inp[2*(J)] * 0.5f, &s1, &c1);                           \
        sincosf(inp[2*(J)+1] * 0.5f, &s2, &c2);                         \
        g[0]=c1*c2;  g[1]=-c1*s2; g[2]=-s1*c2; g[3]=s1*s2;              \
        g[4]=c1*s2;  g[5]=c1*c2;  g[6]=-s1*s2; g[7]=-s1*c2;             \
        g[8]=s1*c2;  g[9]=-s1*s2; g[10]=c1*c2; g[11]=-c1*s2;            \
        g[12]=s1*s2; g[13]=s1*c2; g[14]=c1*s2; g[15]=c1*c2;             \
        sweepR<BBv>(st, g, tid);                                        \
        __syncthreads(); }
    ENC(0, 12) ENC(1, 10) ENC(2, 8) ENC(3, 6) ENC(4, 4) ENC(5, 2) ENC(6, 0)
#undef ENC

    // ---- 13 fused variational blocks (complex 4x4) ----
    float2 G[16];
#define VAR(K, BBv) {                                                   \
        const float2* gp = gates + (K) * 16;                            \
        _Pragma("unroll") for (int r = 0; r < 16; ++r) G[r] = gp[r];    \
        sweepC<BBv>(st, G, tid);                                        \
        __syncthreads(); }
    VAR(0, 12) VAR(1, 10) VAR(2, 8) VAR(3, 6) VAR(4, 4) VAR(5, 2) VAR(6, 0)
    VAR(7, 11) VAR(8, 9) VAR(9, 7) VAR(10, 5) VAR(11, 3) VAR(12, 1)
#undef VAR

    // ---- <Z_q> = sum_i |amp_i|^2 * (1 - 2*bit_{13-q}(i)) ----
    float z[WIRES];
    #pragma unroll
    for (int q = 0; q < WIRES; ++q) z[q] = 0.f;
    #pragma unroll
    for (int it = 0; it < NSTATE / NTH; ++it) {
        int i = tid + it * NTH;
        float2 v = st[phys(i)];
        float pr = v.x * v.x + v.y * v.y;
        #pragma unroll
        for (int q = 0; q < WIRES; ++q) {
            unsigned s = ((unsigned)i << (18 + q)) & 0x80000000u;  // bit (13-q) -> sign
            z[q] += __uint_as_float(__float_as_uint(pr) ^ s);
        }
    }
    #pragma unroll
    for (int q = 0; q < WIRES; ++q) {
        #pragma unroll
        for (int off = 32; off >= 1; off >>= 1)
            z[q] += __shfl_xor(z[q], off, 64);
    }
    __syncthreads();           // state no longer needed; reuse LDS for reduction
    float* part = (float*)st;
    const int lane = tid & 63, wv = tid >> 6;
    if (lane == 0) {
        #pragma unroll
        for (int q = 0; q < WIRES; ++q) part[wv * WIRES + q] = z[q];
    }
    __syncthreads();
    if (tid < WIRES) {
        float s = 0.f;
        #pragma unroll
        for (int w = 0; w < NTH / 64; ++w) s += part[w * WIRES + tid];
        out[b * WIRES + tid] = s;
    }
}

extern "C" void kernel_launch(void* const* d_in, const int* in_sizes, int n_in,
                              void* d_out, int out_size, void* d_ws, size_t ws_size,
                              hipStream_t stream) {
    const float* inputs = (const float*)d_in[0];
    const float* params = (const float*)d_in[1];
    float* out = (float*)d_out;
    float2* gates = (float2*)d_ws;      // 13 * 16 * 8 B = 1664 B scratch

    const int batch = in_sizes[0] / WIRES;
    gate_prep<<<1, 64, 0, stream>>>(params, gates);
    sim<<<batch, NTH, 0, stream>>>(inputs, gates, out);
}

// Round 2
// 154.503 us; speedup vs baseline: 1.3996x; 1.3996x over previous
//
#include <hip/hip_runtime.h>

#define WIRES 14
#define NSTATE (1 << WIRES)   // 16384
#define NTH 1024
#define NVB 13                // variational blocks

__device__ __forceinline__ float2 cmul(float2 a, float2 b) {
    return make_float2(a.x * b.x - a.y * b.y, a.x * b.y + a.y * b.x);
}

// ============ kernel 1: fuse each 10-gate variational block into one 4x4 ============
__global__ void gate_prep(const float* __restrict__ params, float2* __restrict__ G) {
    int k = threadIdx.x;
    if (k >= NVB) return;
    const float* p = params + k * 10;

    float2 U1[4], U2[4], U3[4], U4[4];
    auto rzrx = [](float trx, float trz, float2* U) {
        float cx, sx, cz, sz;
        sincosf(trx * 0.5f, &sx, &cx);
        sincosf(trz * 0.5f, &sz, &cz);
        float2 e0 = make_float2(cz, -sz);   // e^{-i h}
        float2 e1 = make_float2(cz,  sz);   // e^{+i h}
        U[0] = cmul(e0, make_float2(cx, 0.f));
        U[1] = cmul(e0, make_float2(0.f, -sx));
        U[2] = cmul(e1, make_float2(0.f, -sx));
        U[3] = cmul(e1, make_float2(cx, 0.f));
    };
    rzrx(p[0], p[1], U1);   // q1, first
    rzrx(p[2], p[3], U2);   // q2, first
    rzrx(p[5], p[6], U3);   // q1, second
    rzrx(p[7], p[8], U4);   // q2, second

    float2 K12[16], K34[16];
    for (int r1 = 0; r1 < 2; ++r1)
        for (int r2 = 0; r2 < 2; ++r2)
            for (int c1 = 0; c1 < 2; ++c1)
                for (int c2 = 0; c2 < 2; ++c2) {
                    int idx = (r1 * 2 + r2) * 4 + (c1 * 2 + c2);
                    K12[idx] = cmul(U1[r1 * 2 + c1], U2[r2 * 2 + c2]);
                    K34[idx] = cmul(U3[r1 * 2 + c1], U4[r2 * 2 + c2]);
                }

    float2 C1[16], C2[16];
    for (int i = 0; i < 16; ++i) { C1[i] = make_float2(0.f, 0.f); C2[i] = make_float2(0.f, 0.f); }
    {
        float c, s;
        sincosf(p[4] * 0.5f, &s, &c);        // CRY ctrl=q1(high local bit), tgt=q2
        C1[0]  = make_float2(1.f, 0.f); C1[5]  = make_float2(1.f, 0.f);
        C1[10] = make_float2(c, 0.f);   C1[11] = make_float2(-s, 0.f);
        C1[14] = make_float2(s, 0.f);   C1[15] = make_float2(c, 0.f);
        sincosf(p[9] * 0.5f, &s, &c);        // CRY ctrl=q2(low local bit), tgt=q1
        C2[0]  = make_float2(1.f, 0.f); C2[10] = make_float2(1.f, 0.f);
        C2[5]  = make_float2(c, 0.f);   C2[7]  = make_float2(-s, 0.f);
        C2[13] = make_float2(s, 0.f);   C2[15] = make_float2(c, 0.f);
    }

    float2 T1[16], T2[16], Gk[16];
    for (int r = 0; r < 4; ++r)
        for (int c = 0; c < 4; ++c) {
            float2 a = make_float2(0.f, 0.f);
            for (int j = 0; j < 4; ++j) { float2 m = cmul(C1[r*4+j], K12[j*4+c]); a.x += m.x; a.y += m.y; }
            T1[r*4+c] = a;
        }
    for (int r = 0; r < 4; ++r)
        for (int c = 0; c < 4; ++c) {
            float2 a = make_float2(0.f, 0.f);
            for (int j = 0; j < 4; ++j) { float2 m = cmul(K34[r*4+j], T1[j*4+c]); a.x += m.x; a.y += m.y; }
            T2[r*4+c] = a;
        }
    for (int r = 0; r < 4; ++r)
        for (int c = 0; c < 4; ++c) {
            float2 a = make_float2(0.f, 0.f);
            for (int j = 0; j < 4; ++j) { float2 m = cmul(C2[r*4+j], T2[j*4+c]); a.x += m.x; a.y += m.y; }
            Gk[r*4+c] = a;
        }
    for (int i = 0; i < 16; ++i) G[k * 16 + i] = Gk[i];
}

// ============ sim kernel helpers ============

// GF(2)-linear LDS swizzle on float2 index
__device__ __forceinline__ int swz(int i) { return i ^ ((i >> 4) & 15); }

// compile-time: scatter r's 4 bits to global bit positions, then swizzle
template<int B3,int B2,int B1,int B0>
constexpr int prc(int r) {
    int s = ((r&1)?(1<<B0):0) | ((r&2)?(1<<B1):0) | ((r&4)?(1<<B2):0) | ((r&8)?(1<<B3):0);
    return s ^ ((s >> 4) & 15);
}

__device__ __forceinline__ void ld16(float2 g[16], const float2* p) {
    #pragma unroll
    for (int i = 0; i < 16; ++i) g[i] = p[i];
}

// apply complex 4x4 gate on local register-bit pair (PH=high, PL=low)
template<int PH,int PL>
__device__ __forceinline__ void gate4(float2 v[16], const float2 g[16]) {
    constexpr int mask = (1<<PH) | (1<<PL);
    #pragma unroll
    for (int base = 0; base < 16; ++base) {
        if (base & mask) continue;
        const int i0 = base, i1 = base | (1<<PL), i2 = base | (1<<PH), i3 = base | mask;
        float2 v0 = v[i0], v1 = v[i1], v2 = v[i2], v3 = v[i3];
        float2 w0, w1, w2, w3;
#define CROW(R, W)                                                                     \
        W.x = g[4*R+0].x*v0.x - g[4*R+0].y*v0.y + g[4*R+1].x*v1.x - g[4*R+1].y*v1.y    \
            + g[4*R+2].x*v2.x - g[4*R+2].y*v2.y + g[4*R+3].x*v3.x - g[4*R+3].y*v3.y;   \
        W.y = g[4*R+0].x*v0.y + g[4*R+0].y*v0.x + g[4*R+1].x*v1.y + g[4*R+1].y*v1.x    \
            + g[4*R+2].x*v2.y + g[4*R+2].y*v2.x + g[4*R+3].x*v3.y + g[4*R+3].y*v3.x;
        CROW(0, w0) CROW(1, w1) CROW(2, w2) CROW(3, w3)
#undef CROW
        v[i0] = w0; v[i1] = w1; v[i2] = w2; v[i3] = w3;
    }
}

// ============ kernel 2: full per-sample simulation, register-blocked ============
__global__ __launch_bounds__(NTH) void sim(const float* __restrict__ inputs,
                                           const float2* __restrict__ gates,
                                           float* __restrict__ out) {
    __shared__ float2 st[NSTATE];      // 128 KiB state
    __shared__ float2 Fsh[7 * 16];     // fused ENC*G matrices (per-sample); reused as reduce scratch
    const int b = blockIdx.x;
    const int t = threadIdx.x;
    const float* inp = inputs + b * WIRES;

    // ---- lanes 0..6: fuse ENC pair j (RY kron) into layer-1 block G_j : F = G * E ----
    if (t < 7) {
        const int j = t;
        float c1, s1, c2, s2;
        sincosf(inp[2*j]     * 0.5f, &s1, &c1);
        sincosf(inp[2*j + 1] * 0.5f, &s2, &c2);
        float E[16] = { c1*c2, -c1*s2, -s1*c2,  s1*s2,
                        c1*s2,  c1*c2, -s1*s2, -s1*c2,
                        s1*c2, -s1*s2,  c1*c2, -c1*s2,
                        s1*s2,  s1*c2,  c1*s2,  c1*c2 };
        const float2* Gj = gates + j * 16;
        #pragma unroll
        for (int r = 0; r < 4; ++r)
            #pragma unroll
            for (int c = 0; c < 4; ++c) {
                float2 a = make_float2(0.f, 0.f);
                #pragma unroll
                for (int k = 0; k < 4; ++k) {
                    a.x += Gj[r*4+k].x * E[k*4+c];
                    a.y += Gj[r*4+k].y * E[k*4+c];
                }
                Fsh[j*16 + r*4 + c] = a;
            }
    }
    __syncthreads();

    float2 v[16], g[16];

    // ---- P1: register bits {13,12,11,10}; state = |0..0> directly ----
    {
        #pragma unroll
        for (int r = 0; r < 16; ++r) v[r] = make_float2(0.f, 0.f);
        if (t == 0) v[0].x = 1.f;
        ld16(g, Fsh + 0*16);      gate4<3,2>(v, g);   // ENC0*G0 on (13,12)
        ld16(g, Fsh + 1*16);      gate4<1,0>(v, g);   // ENC1*G1 on (11,10)
        ld16(g, gates + 7*16);    gate4<2,1>(v, g);   // G7 on (12,11)
        const int pb = swz(t);                         // tb = t (bits 9..0)
        #pragma unroll
        for (int r = 0; r < 16; ++r) st[pb ^ prc<13,12,11,10>(r)] = v[r];
    }
    __syncthreads();

    // ---- P2: register bits {9,8,7,6} ----
    {
        const int tb = (t & 63) | ((t & 0x3C0) << 4);
        const int pb = swz(tb);
        #pragma unroll
        for (int r = 0; r < 16; ++r) v[r] = st[pb ^ prc<9,8,7,6>(r)];
        ld16(g, Fsh + 2*16);      gate4<3,2>(v, g);   // ENC2*G2 on (9,8)
        ld16(g, Fsh + 3*16);      gate4<1,0>(v, g);   // ENC3*G3 on (7,6)
        ld16(g, gates + 9*16);    gate4<2,1>(v, g);   // G9 on (8,7)
        #pragma unroll
        for (int r = 0; r < 16; ++r) st[pb ^ prc<9,8,7,6>(r)] = v[r];
    }
    __syncthreads();

    // ---- P3: register bits {5,4,3,2} ----
    {
        const int tb = (t & 3) | ((t & 0x3FC) << 4);
        const int pb = swz(tb);
        #pragma unroll
        for (int r = 0; r < 16; ++r) v[r] = st[pb ^ prc<5,4,3,2>(r)];
        ld16(g, Fsh + 4*16);      gate4<3,2>(v, g);   // ENC4*G4 on (5,4)
        ld16(g, Fsh + 5*16);      gate4<1,0>(v, g);   // ENC5*G5 on (3,2)
        ld16(g, gates + 11*16);   gate4<2,1>(v, g);   // G11 on (4,3)
        #pragma unroll
        for (int r = 0; r < 16; ++r) st[pb ^ prc<5,4,3,2>(r)] = v[r];
    }
    __syncthreads();

    // ---- P4: register bits {3,2,1,0} ----
    {
        const int tb = t << 4;
        const int pb = swz(tb);
        #pragma unroll
        for (int r = 0; r < 16; ++r) v[r] = st[pb ^ prc<3,2,1,0>(r)];
        ld16(g, Fsh + 6*16);      gate4<1,0>(v, g);   // ENC6*G6 on (1,0)
        ld16(g, gates + 12*16);   gate4<2,1>(v, g);   // G12 on (2,1)
        #pragma unroll
        for (int r = 0; r < 16; ++r) st[pb ^ prc<3,2,1,0>(r)] = v[r];
    }
    __syncthreads();

    // ---- P5: register bits {10,9,6,5}; reduce directly from registers ----
    int tb5;
    {
        tb5 = (t & 31) | ((t & 0x60) << 2) | ((t & 0x380) << 4);
        const int pb = swz(tb5);
        #pragma unroll
        for (int r = 0; r < 16; ++r) v[r] = st[pb ^ prc<10,9,6,5>(r)];
        ld16(g, gates + 8*16);    gate4<3,2>(v, g);   // G8 on (10,9)
        ld16(g, gates + 10*16);   gate4<1,0>(v, g);   // G10 on (6,5)
    }

    // ---- <Z>: per-thread partials from registers ----
    float pr[16], S = 0.f;
    #pragma unroll
    for (int r = 0; r < 16; ++r) { pr[r] = v[r].x * v[r].x + v[r].y * v[r].y; S += pr[r]; }
    float s5 = 0.f, s6 = 0.f, s9 = 0.f, s10 = 0.f;   // sums where that R-bit is 1
    #pragma unroll
    for (int r = 0; r < 16; ++r) {
        if (r & 1) s5  += pr[r];
        if (r & 2) s6  += pr[r];
        if (r & 4) s9  += pr[r];
        if (r & 8) s10 += pr[r];
    }
    float zq[WIRES];
    #pragma unroll
    for (int q = 0; q < WIRES; ++q) {
        const int bb = 13 - q;
        if      (bb == 10) zq[q] = S - 2.f * s10;
        else if (bb == 9)  zq[q] = S - 2.f * s9;
        else if (bb == 6)  zq[q] = S - 2.f * s6;
        else if (bb == 5)  zq[q] = S - 2.f * s5;
        else               zq[q] = ((tb5 >> bb) & 1) ? -S : S;
    }
    #pragma unroll
    for (int q = 0; q < WIRES; ++q) {
        #pragma unroll
        for (int off = 32; off >= 1; off >>= 1)
            zq[q] += __shfl_xor(zq[q], off, 64);
    }
    __syncthreads();                    // all P5 state reads done; reuse Fsh as scratch
    float* part = (float*)Fsh;          // 16 waves * 14 floats = 896 B = sizeof(Fsh)
    const int lane = t & 63, wv = t >> 6;
    if (lane == 0) {
        #pragma unroll
        for (int q = 0; q < WIRES; ++q) part[wv * WIRES + q] = zq[q];
    }
    __syncthreads();
    if (t < WIRES) {
        float s = 0.f;
        #pragma unroll
        for (int w = 0; w < NTH / 64; ++w) s += part[w * WIRES + t];
        out[b * WIRES + t] = s;
    }
}

extern "C" void kernel_launch(void* const* d_in, const int* in_sizes, int n_in,
                              void* d_out, int out_size, void* d_ws, size_t ws_size,
                              hipStream_t stream) {
    const float* inputs = (const float*)d_in[0];
    const float* params = (const float*)d_in[1];
    float* out = (float*)d_out;
    float2* gates = (float2*)d_ws;      // 13 * 16 * 8 B = 1664 B scratch

    const int batch = in_sizes[0] / WIRES;
    gate_prep<<<1, 64, 0, stream>>>(params, gates);
    sim<<<batch, NTH, 0, stream>>>(inputs, gates, out);
}

// Round 3
// 154.323 us; speedup vs baseline: 1.4012x; 1.0012x over previous
//
#include <hip/hip_runtime.h>

#define WIRES 14
#define NSTATE (1 << WIRES)   // 16384
#define NTH 1024
#define NVB 13                // variational blocks

__device__ __forceinline__ float2 cmul(float2 a, float2 b) {
    return make_float2(a.x * b.x - a.y * b.y, a.x * b.y + a.y * b.x);
}

// ============ kernel 1: fuse each 10-gate variational block into one 4x4 ============
__global__ void gate_prep(const float* __restrict__ params, float2* __restrict__ G) {
    int k = threadIdx.x;
    if (k >= NVB) return;
    const float* p = params + k * 10;

    float2 U1[4], U2[4], U3[4], U4[4];
    auto rzrx = [](float trx, float trz, float2* U) {
        float cx, sx, cz, sz;
        sincosf(trx * 0.5f, &sx, &cx);
        sincosf(trz * 0.5f, &sz, &cz);
        float2 e0 = make_float2(cz, -sz);   // e^{-i h}
        float2 e1 = make_float2(cz,  sz);   // e^{+i h}
        U[0] = cmul(e0, make_float2(cx, 0.f));
        U[1] = cmul(e0, make_float2(0.f, -sx));
        U[2] = cmul(e1, make_float2(0.f, -sx));
        U[3] = cmul(e1, make_float2(cx, 0.f));
    };
    rzrx(p[0], p[1], U1);   // q1, first
    rzrx(p[2], p[3], U2);   // q2, first
    rzrx(p[5], p[6], U3);   // q1, second
    rzrx(p[7], p[8], U4);   // q2, second

    float2 K12[16], K34[16];
    for (int r1 = 0; r1 < 2; ++r1)
        for (int r2 = 0; r2 < 2; ++r2)
            for (int c1 = 0; c1 < 2; ++c1)
                for (int c2 = 0; c2 < 2; ++c2) {
                    int idx = (r1 * 2 + r2) * 4 + (c1 * 2 + c2);
                    K12[idx] = cmul(U1[r1 * 2 + c1], U2[r2 * 2 + c2]);
                    K34[idx] = cmul(U3[r1 * 2 + c1], U4[r2 * 2 + c2]);
                }

    float2 C1[16], C2[16];
    for (int i = 0; i < 16; ++i) { C1[i] = make_float2(0.f, 0.f); C2[i] = make_float2(0.f, 0.f); }
    {
        float c, s;
        sincosf(p[4] * 0.5f, &s, &c);        // CRY ctrl=q1(high local bit), tgt=q2
        C1[0]  = make_float2(1.f, 0.f); C1[5]  = make_float2(1.f, 0.f);
        C1[10] = make_float2(c, 0.f);   C1[11] = make_float2(-s, 0.f);
        C1[14] = make_float2(s, 0.f);   C1[15] = make_float2(c, 0.f);
        sincosf(p[9] * 0.5f, &s, &c);        // CRY ctrl=q2(low local bit), tgt=q1
        C2[0]  = make_float2(1.f, 0.f); C2[10] = make_float2(1.f, 0.f);
        C2[5]  = make_float2(c, 0.f);   C2[7]  = make_float2(-s, 0.f);
        C2[13] = make_float2(s, 0.f);   C2[15] = make_float2(c, 0.f);
    }

    float2 T1[16], T2[16], Gk[16];
    for (int r = 0; r < 4; ++r)
        for (int c = 0; c < 4; ++c) {
            float2 a = make_float2(0.f, 0.f);
            for (int j = 0; j < 4; ++j) { float2 m = cmul(C1[r*4+j], K12[j*4+c]); a.x += m.x; a.y += m.y; }
            T1[r*4+c] = a;
        }
    for (int r = 0; r < 4; ++r)
        for (int c = 0; c < 4; ++c) {
            float2 a = make_float2(0.f, 0.f);
            for (int j = 0; j < 4; ++j) { float2 m = cmul(K34[r*4+j], T1[j*4+c]); a.x += m.x; a.y += m.y; }
            T2[r*4+c] = a;
        }
    for (int r = 0; r < 4; ++r)
        for (int c = 0; c < 4; ++c) {
            float2 a = make_float2(0.f, 0.f);
            for (int j = 0; j < 4; ++j) { float2 m = cmul(C2[r*4+j], T2[j*4+c]); a.x += m.x; a.y += m.y; }
            Gk[r*4+c] = a;
        }
    for (int i = 0; i < 16; ++i) G[k * 16 + i] = Gk[i];
}

// ============ sim kernel helpers ============

// GF(2)-linear LDS swizzle on float2 index
__device__ __forceinline__ int swz(int i) { return i ^ ((i >> 4) & 15); }

// compile-time: scatter r's 4 bits to global bit positions, then swizzle
template<int B3,int B2,int B1,int B0>
constexpr int prc(int r) {
    int s = ((r&1)?(1<<B0):0) | ((r&2)?(1<<B1):0) | ((r&4)?(1<<B2):0) | ((r&8)?(1<<B3):0);
    return s ^ ((s >> 4) & 15);
}

__device__ __forceinline__ void ld16(float2 g[16], const float2* p) {
    #pragma unroll
    for (int i = 0; i < 16; ++i) g[i] = p[i];
}

// apply complex 4x4 gate on local register-bit pair (PH=high, PL=low)
template<int PH,int PL>
__device__ __forceinline__ void gate4(float2 v[16], const float2 g[16]) {
    constexpr int mask = (1<<PH) | (1<<PL);
    #pragma unroll
    for (int base = 0; base < 16; ++base) {
        if (base & mask) continue;
        const int i0 = base, i1 = base | (1<<PL), i2 = base | (1<<PH), i3 = base | mask;
        float2 v0 = v[i0], v1 = v[i1], v2 = v[i2], v3 = v[i3];
        float2 w0, w1, w2, w3;
#define CROW(R, W)                                                                     \
        W.x = g[4*R+0].x*v0.x - g[4*R+0].y*v0.y + g[4*R+1].x*v1.x - g[4*R+1].y*v1.y    \
            + g[4*R+2].x*v2.x - g[4*R+2].y*v2.y + g[4*R+3].x*v3.x - g[4*R+3].y*v3.y;   \
        W.y = g[4*R+0].x*v0.y + g[4*R+0].y*v0.x + g[4*R+1].x*v1.y + g[4*R+1].y*v1.x    \
            + g[4*R+2].x*v2.y + g[4*R+2].y*v2.x + g[4*R+3].x*v3.y + g[4*R+3].y*v3.x;
        CROW(0, w0) CROW(1, w1) CROW(2, w2) CROW(3, w3)
#undef CROW
        v[i0] = w0; v[i1] = w1; v[i2] = w2; v[i3] = w3;
    }
}

// ============ kernel 2: full per-sample simulation, register-blocked ============
// LDS (128 KiB) caps residency at 1 block/CU = 4 waves/SIMD, so ask for exactly
// that (2nd launch-bounds arg = min waves/EU): raises VGPR cap 64 -> 128 and
// eliminates the ~26 MB/dispatch scratch-spill traffic seen at VGPR=64.
__global__ __launch_bounds__(NTH, 4) void sim(const float* __restrict__ inputs,
                                              const float2* __restrict__ gates,
                                              float* __restrict__ out) {
    __shared__ float2 st[NSTATE];      // 128 KiB state
    __shared__ float2 Fsh[7 * 16];     // fused ENC*G matrices (per-sample); reused as reduce scratch
    const int b = blockIdx.x;
    const int t = threadIdx.x;
    const float* inp = inputs + b * WIRES;

    // ---- lanes 0..6: fuse ENC pair j (RY kron) into layer-1 block G_j : F = G * E ----
    if (t < 7) {
        const int j = t;
        float c1, s1, c2, s2;
        sincosf(inp[2*j]     * 0.5f, &s1, &c1);
        sincosf(inp[2*j + 1] * 0.5f, &s2, &c2);
        float E[16] = { c1*c2, -c1*s2, -s1*c2,  s1*s2,
                        c1*s2,  c1*c2, -s1*s2, -s1*c2,
                        s1*c2, -s1*s2,  c1*c2, -c1*s2,
                        s1*s2,  s1*c2,  c1*s2,  c1*c2 };
        const float2* Gj = gates + j * 16;
        #pragma unroll
        for (int r = 0; r < 4; ++r)
            #pragma unroll
            for (int c = 0; c < 4; ++c) {
                float2 a = make_float2(0.f, 0.f);
                #pragma unroll
                for (int k = 0; k < 4; ++k) {
                    a.x += Gj[r*4+k].x * E[k*4+c];
                    a.y += Gj[r*4+k].y * E[k*4+c];
                }
                Fsh[j*16 + r*4 + c] = a;
            }
    }
    __syncthreads();

    float2 v[16], g[16];

    // ---- P1: register bits {13,12,11,10}; state = |0..0> directly ----
    {
        #pragma unroll
        for (int r = 0; r < 16; ++r) v[r] = make_float2(0.f, 0.f);
        if (t == 0) v[0].x = 1.f;
        ld16(g, Fsh + 0*16);      gate4<3,2>(v, g);   // ENC0*G0 on (13,12)
        ld16(g, Fsh + 1*16);      gate4<1,0>(v, g);   // ENC1*G1 on (11,10)
        ld16(g, gates + 7*16);    gate4<2,1>(v, g);   // G7 on (12,11)
        const int pb = swz(t);                         // tb = t (bits 9..0)
        #pragma unroll
        for (int r = 0; r < 16; ++r) st[pb ^ prc<13,12,11,10>(r)] = v[r];
    }
    __syncthreads();

    // ---- P2: register bits {9,8,7,6} ----
    {
        const int tb = (t & 63) | ((t & 0x3C0) << 4);
        const int pb = swz(tb);
        #pragma unroll
        for (int r = 0; r < 16; ++r) v[r] = st[pb ^ prc<9,8,7,6>(r)];
        ld16(g, Fsh + 2*16);      gate4<3,2>(v, g);   // ENC2*G2 on (9,8)
        ld16(g, Fsh + 3*16);      gate4<1,0>(v, g);   // ENC3*G3 on (7,6)
        ld16(g, gates + 9*16);    gate4<2,1>(v, g);   // G9 on (8,7)
        #pragma unroll
        for (int r = 0; r < 16; ++r) st[pb ^ prc<9,8,7,6>(r)] = v[r];
    }
    __syncthreads();

    // ---- P3: register bits {5,4,3,2} ----
    {
        const int tb = (t & 3) | ((t & 0x3FC) << 4);
        const int pb = swz(tb);
        #pragma unroll
        for (int r = 0; r < 16; ++r) v[r] = st[pb ^ prc<5,4,3,2>(r)];
        ld16(g, Fsh + 4*16);      gate4<3,2>(v, g);   // ENC4*G4 on (5,4)
        ld16(g, Fsh + 5*16);      gate4<1,0>(v, g);   // ENC5*G5 on (3,2)
        ld16(g, gates + 11*16);   gate4<2,1>(v, g);   // G11 on (4,3)
        #pragma unroll
        for (int r = 0; r < 16; ++r) st[pb ^ prc<5,4,3,2>(r)] = v[r];
    }
    __syncthreads();

    // ---- P4: register bits {3,2,1,0} ----
    {
        const int tb = t << 4;
        const int pb = swz(tb);
        #pragma unroll
        for (int r = 0; r < 16; ++r) v[r] = st[pb ^ prc<3,2,1,0>(r)];
        ld16(g, Fsh + 6*16);      gate4<1,0>(v, g);   // ENC6*G6 on (1,0)
        ld16(g, gates + 12*16);   gate4<2,1>(v, g);   // G12 on (2,1)
        #pragma unroll
        for (int r = 0; r < 16; ++r) st[pb ^ prc<3,2,1,0>(r)] = v[r];
    }
    __syncthreads();

    // ---- P5: register bits {10,9,6,5}; reduce directly from registers ----
    int tb5;
    {
        tb5 = (t & 31) | ((t & 0x60) << 2) | ((t & 0x380) << 4);
        const int pb = swz(tb5);
        #pragma unroll
        for (int r = 0; r < 16; ++r) v[r] = st[pb ^ prc<10,9,6,5>(r)];
        ld16(g, gates + 8*16);    gate4<3,2>(v, g);   // G8 on (10,9)
        ld16(g, gates + 10*16);   gate4<1,0>(v, g);   // G10 on (6,5)
    }

    // ---- <Z>: per-thread partials from registers ----
    float pr[16], S = 0.f;
    #pragma unroll
    for (int r = 0; r < 16; ++r) { pr[r] = v[r].x * v[r].x + v[r].y * v[r].y; S += pr[r]; }
    float s5 = 0.f, s6 = 0.f, s9 = 0.f, s10 = 0.f;   // sums where that R-bit is 1
    #pragma unroll
    for (int r = 0; r < 16; ++r) {
        if (r & 1) s5  += pr[r];
        if (r & 2) s6  += pr[r];
        if (r & 4) s9  += pr[r];
        if (r & 8) s10 += pr[r];
    }
    float zq[WIRES];
    #pragma unroll
    for (int q = 0; q < WIRES; ++q) {
        const int bb = 13 - q;
        if      (bb == 10) zq[q] = S - 2.f * s10;
        else if (bb == 9)  zq[q] = S - 2.f * s9;
        else if (bb == 6)  zq[q] = S - 2.f * s6;
        else if (bb == 5)  zq[q] = S - 2.f * s5;
        else               zq[q] = ((tb5 >> bb) & 1) ? -S : S;
    }
    #pragma unroll
    for (int q = 0; q < WIRES; ++q) {
        #pragma unroll
        for (int off = 32; off >= 1; off >>= 1)
            zq[q] += __shfl_xor(zq[q], off, 64);
    }
    __syncthreads();                    // all P5 state reads done; reuse Fsh as scratch
    float* part = (float*)Fsh;          // 16 waves * 14 floats = 896 B = sizeof(Fsh)
    const int lane = t & 63, wv = t >> 6;
    if (lane == 0) {
        #pragma unroll
        for (int q = 0; q < WIRES; ++q) part[wv * WIRES + q] = zq[q];
    }
    __syncthreads();
    if (t < WIRES) {
        float s = 0.f;
        #pragma unroll
        for (int w = 0; w < NTH / 64; ++w) s += part[w * WIRES + t];
        out[b * WIRES + t] = s;
    }
}

extern "C" void kernel_launch(void* const* d_in, const int* in_sizes, int n_in,
                              void* d_out, int out_size, void* d_ws, size_t ws_size,
                              hipStream_t stream) {
    const float* inputs = (const float*)d_in[0];
    const float* params = (const float*)d_in[1];
    float* out = (float*)d_out;
    float2* gates = (float2*)d_ws;      // 13 * 16 * 8 B = 1664 B scratch

    const int batch = in_sizes[0] / WIRES;
    gate_prep<<<1, 64, 0, stream>>>(params, gates);
    sim<<<batch, NTH, 0, stream>>>(inputs, gates, out);
}